// Round 8
// baseline (151.668 us; speedup 1.0000x reference)
//
#include <hip/hip_runtime.h>
#include <hip/hip_bf16.h>

// ---------------------------------------------------------------------------
// TwoSimplicialAttention  (B=2, T=192, C=512, H=8, D=64)
// R12: (a) attn reverted to R10's proven per-m interleaved loop (51.0us),
//      with #pragma unroll 2 on the kstep loop for cross-iteration ILP.
//      (b) norm+outp FUSED into outp2 (48 blocks x 256thr): each block
//      normalizes its 16 output rows from accp directly into LDS (bf16
//      hi/lo), then GEMMs against W_out^T with depth-1 B-prefetch.
//      Kills one launch (~10us), norm exec, and the OH/OL HBM round-trip.
//      Pipeline: prep -> proj -> attn -> outp2 (4 launches, was 5).
// ---------------------------------------------------------------------------

typedef float  v4f __attribute__((ext_vector_type(4)));
typedef short  v8s __attribute__((ext_vector_type(8)));

__device__ __forceinline__ unsigned short f2bf(float f) {
  unsigned u = __float_as_uint(f);
  u += 0x7fffu + ((u >> 16) & 1u);       // RNE
  return (unsigned short)(u >> 16);
}
__device__ __forceinline__ float bf2f(unsigned short b) {
  return __uint_as_float(((unsigned)b) << 16);
}
__device__ __forceinline__ unsigned pack_bf16(float lo, float hi) {
  __hip_bfloat162 t = __float22bfloat162_rn(float2{lo, hi});
  union { __hip_bfloat162 b; unsigned u; } cv;
  cv.b = t;
  return cv.u;
}

#if __has_builtin(__builtin_amdgcn_exp2f)
#define EXP2F(x) __builtin_amdgcn_exp2f(x)
#else
#define EXP2F(x) exp2f(x)
#endif

#define MFMA32(a, b, c) __builtin_amdgcn_mfma_f32_16x16x32_bf16((a), (b), (c), 0, 0, 0)

// q scale = D^-0.5 * log2(e)
#define QSCALE 0.18033688011112042f

// ws layout, floats (wsf):
//   qs   [16][192][64]        @ 0        (q * 0.125*log2e, fp32)
//   v2p  [16][192][64]        @ 196608   (fp32, linear [k][d])
//   accp [16][12][4][16][64]  @ 393216
//   Sp   [16][12][4][16]      @ 1179648  (total fp32: 1191936)
// ws layout, ushort (wsh = wsf + 1191936):
//   k1b  [16][192][64]  @ 0
//   k2b  [16][192][64]  @ 196608
//   v1t  [16][64][192]  @ 393216   (columns PERMUTED within 32-chunks)
//   xh   [384][512]     @ 589824      xl @ 786432
//   Wth  [2560][512]    @ 983040      Wtl @ 2293760   (W_in^T, k-major)
//   Woth [512][512]     @ 3604480     Wotl @ 3866624  (W_out^T, k-major)

#define XH_OFF   589824
#define XL_OFF   786432
#define WTH_OFF  983040
#define WTL_OFF  2293760
#define WOTH_OFF 3604480
#define WOTL_OFF 3866624

// V1 column position for j-offset t within a 32-chunk (R10 ordering):
//   quad = (t>>2)&3, hi = (t>>4)&1, r = t&3  ->  p = quad*8 + hi*4 + r
// inverse: t = ((p>>3)&3)<<2 | ((p>>2)&1)<<4 | (p&3)
__device__ __forceinline__ int v1perm_inv(int p) {
  return (((p >> 3) & 3) << 2) | (((p >> 2) & 1) << 4) | (p & 3);
}

// ------------------------------ Phase 0: prep ------------------------------
// grid 864: [0,640) W_in transpose+split (64n x 32k tiles), [640,768) W_out,
// [768,864) x hi/lo split. W goes through LDS so global writes are dense.
__global__ __launch_bounds__(256) void prep_kernel(
    const float* __restrict__ x, const float* __restrict__ Win,
    const float* __restrict__ Wout, unsigned short* __restrict__ wsh) {
  __shared__ float tile[32 * 65];
  const int bi = blockIdx.x, t = threadIdx.x;
  if (bi < 768) {
    const float* W; unsigned short *Th, *Tl; int R, n0, k0;
    if (bi < 640) {
      W = Win; Th = wsh + WTH_OFF; Tl = wsh + WTL_OFF; R = 2560;
      n0 = (bi % 40) << 6; k0 = (bi / 40) << 5;
    } else {
      const int idx = bi - 640;
      W = Wout; Th = wsh + WOTH_OFF; Tl = wsh + WOTL_OFF; R = 512;
      n0 = (idx & 7) << 6; k0 = (idx >> 3) << 5;
    }
    // phase 1: coalesced reads -> LDS [k][n] (pad 65)
    const int n = t & 63, kq = (t >> 6) * 8;
#pragma unroll
    for (int j = 0; j < 8; ++j)
      tile[(kq + j) * 65 + n] = W[(k0 + kq + j) * R + n0 + n];
    __syncthreads();
    // phase 2: k-contig hi/lo writes (dense 64B lines)
    const int n2 = t >> 2, ks = (t & 3) * 8;
    union { uint4 u; unsigned short us[8]; } ph, pl;
#pragma unroll
    for (int j = 0; j < 8; ++j) {
      const float v = tile[(ks + j) * 65 + n2];
      const unsigned short h = f2bf(v);
      ph.us[j] = h;
      pl.us[j] = f2bf(v - bf2f(h));
    }
    *(uint4*)(Th + (n0 + n2) * 512 + k0 + ks) = ph.u;
    *(uint4*)(Tl + (n0 + n2) * 512 + k0 + ks) = pl.u;
  } else {
    const int flat = ((bi - 768) * 256 + t) * 8;
    const v4f v0 = *(const v4f*)(x + flat);
    const v4f v1 = *(const v4f*)(x + flat + 4);
    union { uint4 u; unsigned short us[8]; } ph, pl;
#pragma unroll
    for (int j = 0; j < 4; ++j) {
      unsigned short h = f2bf(v0[j]);
      ph.us[j] = h; pl.us[j] = f2bf(v0[j] - bf2f(h));
      h = f2bf(v1[j]);
      ph.us[4 + j] = h; pl.us[4 + j] = f2bf(v1[j] - bf2f(h));
    }
    *(uint4*)(wsh + XH_OFF + flat) = ph.u;
    *(uint4*)(wsh + XL_OFF + flat) = pl.u;
  }
}

// ------------------------------ Phase 1: proj (bf16x3 MFMA) ----------------
// grid 960 x 64thr: 1 wave/block, 32x32 C-tile, prefetch depth 2.
// Epilogue: LDS tile -> coalesced per-which stores (tile-constant which/bh).
__global__ __launch_bounds__(64) void proj_kernel(
    const unsigned short* __restrict__ wsh, const float* __restrict__ bin,
    float* __restrict__ wsf, unsigned short* __restrict__ wshd) {
  __shared__ float tile[32 * 33];
  const int lane = threadIdx.x;
  const int c = lane & 15, q = lane >> 4;
  const int bm = blockIdx.x % 12, bn = blockIdx.x / 12;

  const unsigned short* base[8];
  base[0] = wsh + XH_OFF + (bm * 32 + c) * 512 + (q << 3);
  base[1] = base[0] + 16 * 512;
  base[2] = wsh + XL_OFF + (bm * 32 + c) * 512 + (q << 3);
  base[3] = base[2] + 16 * 512;
  base[4] = wsh + WTH_OFF + (bn * 32 + c) * 512 + (q << 3);
  base[5] = base[4] + 16 * 512;
  base[6] = wsh + WTL_OFF + (bn * 32 + c) * 512 + (q << 3);
  base[7] = base[6] + 16 * 512;

  const v4f z = {0.f, 0.f, 0.f, 0.f};
  v4f a00 = z, a01 = z, a10 = z, a11 = z;

  v8s cur[8], nxt[8];
#pragma unroll
  for (int i = 0; i < 8; ++i) cur[i] = *(const v8s*)(base[i]);
#pragma unroll
  for (int i = 0; i < 8; ++i) nxt[i] = *(const v8s*)(base[i] + 32);

#pragma unroll 1
  for (int ks = 0; ks < 16; ++ks) {
    v8s nx2[8];
    if (ks < 14) {
      const int o = (ks + 2) * 32;
#pragma unroll
      for (int i = 0; i < 8; ++i) nx2[i] = *(const v8s*)(base[i] + o);
    }
    // Ah0,Ah1,Al0,Al1 = cur[0..3]; Bh0,Bh1,Bl0,Bl1 = cur[4..7]
    a00 = MFMA32(cur[2], cur[4], a00); a00 = MFMA32(cur[0], cur[6], a00); a00 = MFMA32(cur[0], cur[4], a00);
    a01 = MFMA32(cur[2], cur[5], a01); a01 = MFMA32(cur[0], cur[7], a01); a01 = MFMA32(cur[0], cur[5], a01);
    a10 = MFMA32(cur[3], cur[4], a10); a10 = MFMA32(cur[1], cur[6], a10); a10 = MFMA32(cur[1], cur[4], a10);
    a11 = MFMA32(cur[3], cur[5], a11); a11 = MFMA32(cur[1], cur[7], a11); a11 = MFMA32(cur[1], cur[5], a11);
#pragma unroll
    for (int i = 0; i < 8; ++i) { cur[i] = nxt[i]; nxt[i] = nx2[i]; }
  }

  // ---- epilogue via LDS tile (coalesced stores) ----
  const int n0 = bn * 32;
  const int which = n0 >> 9;
  const int h  = (n0 & 511) >> 6;
  const int d0 = n0 & 63;                 // 0 or 32
  const int b  = (bm >= 6) ? 1 : 0;
  const int bh = b * 8 + h;
  const int tt0 = (bm - b * 6) * 32;

  v4f accs[2][2] = {{a00, a01}, {a10, a11}};
#pragma unroll
  for (int mt = 0; mt < 2; ++mt)
#pragma unroll
    for (int nt = 0; nt < 2; ++nt) {
      const float bv = bin[n0 + nt * 16 + c];
#pragma unroll
      for (int r = 0; r < 4; ++r)
        tile[(mt * 16 + (q << 2) + r) * 33 + nt * 16 + c] = accs[mt][nt][r] + bv;
    }
  __syncthreads();

  const int rr = lane >> 1, cc0 = (lane & 1) * 16;
  if (which == 0 || which == 4) {
    float* out = wsf + (which == 4 ? 196608 : 0) + ((bh * 192 + tt0 + rr) << 6) + d0 + cc0;
    const float s = (which == 0) ? QSCALE : 1.0f;
#pragma unroll
    for (int i = 0; i < 16; i += 4) {
      v4f v;
#pragma unroll
      for (int j = 0; j < 4; ++j) v[j] = tile[rr * 33 + cc0 + i + j] * s;
      *(v4f*)(out + i) = v;
    }
  } else if (which == 1 || which == 3) {
    unsigned short* out = wshd + (which == 3 ? 196608 : 0) + ((bh * 192 + tt0 + rr) << 6) + d0 + cc0;
#pragma unroll
    for (int hf = 0; hf < 2; ++hf) {
      union { uint4 u; unsigned short us[8]; } pk;
#pragma unroll
      for (int j = 0; j < 8; ++j) pk.us[j] = f2bf(tile[rr * 33 + cc0 + hf * 8 + j]);
      *(uint4*)(out + hf * 8) = pk.u;
    }
  } else {  // which == 2: v1t, transposed + permuted (column reads from LDS)
    const int dd = rr, p0 = cc0;
    unsigned short* out = wshd + 393216 + ((bh << 6) + d0 + dd) * 192 + tt0 + p0;
#pragma unroll
    for (int hf = 0; hf < 2; ++hf) {
      union { uint4 u; unsigned short us[8]; } pk;
#pragma unroll
      for (int j = 0; j < 8; ++j) {
        const int p = p0 + hf * 8 + j;
        pk.us[j] = f2bf(tile[v1perm_inv(p) * 33 + dd]);
      }
      *(uint4*)(out + hf * 8) = pk.u;
    }
  }
}

// ------------------------------ Phase 2: attention -------------------------
// grid = 16(bh)*12(i)*4(ksplit) = 768 blocks, 256 thr (4 waves).
// R10 structure (proven 51.0us): wave (jh,kh) does 6 jt x 24 ksteps; P stays
// in registers via operand-swapped MFMAs; per-m interleaved body.
// #pragma unroll 2 for cross-iteration ILP.
__global__ __launch_bounds__(256, 2) void attn_kernel(
    const float* __restrict__ wsf, const unsigned short* __restrict__ wsh,
    float* __restrict__ accp, float* __restrict__ Sp) {
  __shared__ char smem[17408];
  unsigned short* K2s = (unsigned short*)smem;            // [48][64]

  const int tid  = threadIdx.x;
  const int wv   = tid >> 6;
  const int lane = tid & 63;
  const int c    = lane & 15;
  const int quad = lane >> 4;
  const int jh   = wv & 1;
  const int kh   = wv >> 1;

  const int bb = blockIdx.x;
  const int kb = bb & 3;
  const int it = (bb >> 2) % 12;
  const int bh = bb / 48;

  const unsigned short* k1g = wsh + bh * 192 * 64;
  const unsigned short* v1g = wsh + 393216 + bh * 64 * 192;
  const unsigned short* k2g = wsh + 196608 + bh * 192 * 64;
  const float*          v2g = wsf + 196608 + bh * 12288;   // [192][64] f32

  // stage this block's 48 k2 rows (only LDS staging left)
  for (int idx = tid; idx < 384; idx += 256) {
    const int r = idx >> 3, c8 = (idx & 7) * 8;
    *(uint4*)(K2s + r * 64 + c8) = *(const uint4*)(k2g + (kb * 48 + r) * 64 + c8);
  }

  // K1 A-frags (this wave's 6 jt): frag[j][h] = K1[(jh*6+j)*16+c][h*32+quad*8..+8]
  v8s k1f[6][2];
#pragma unroll
  for (int j = 0; j < 6; ++j) {
    const unsigned short* kp = k1g + (((jh * 6 + j) * 16 + c) << 6) + (quad << 3);
    k1f[j][0] = *(const v8s*)(kp);
    k1f[j][1] = *(const v8s*)(kp + 32);
  }

  // PV A-frags (kstep-invariant): vf[m][dt] = V1t[d=dt*16+c][chunk(jh*3+m), pos quad*8..+8]
  v8s vf[3][4];
#pragma unroll
  for (int m = 0; m < 3; ++m)
#pragma unroll
    for (int dt = 0; dt < 4; ++dt)
      vf[m][dt] = *(const v8s*)(v1g + (dt * 16 + c) * 192 + ((jh * 3 + m) << 5) + (quad << 3));

  // q rows (fp32, pre-scaled): i = it*16+c, d = quad*8+e (+32)
  const float* qg = wsf + ((bh * 192 + it * 16 + c) << 6) + (quad << 3);
  float q0[8], q1[8];
  {
    v4f qa = *(const v4f*)(qg), qb = *(const v4f*)(qg + 4);
    v4f qc = *(const v4f*)(qg + 32), qd = *(const v4f*)(qg + 36);
#pragma unroll
    for (int e = 0; e < 4; ++e) {
      q0[e] = qa[e]; q0[4 + e] = qb[e];
      q1[e] = qc[e]; q1[4 + e] = qd[e];
    }
  }
  __syncthreads();   // K2s staged; no barriers until epilogue

  const v4f z = {0.f, 0.f, 0.f, 0.f};
  v4f acc[4] = {z, z, z, z};
  float sS = 0.f;

  union U4 { uint4 u4; unsigned short us[8]; };
  union AF { v8s v; unsigned u[4]; };

#pragma unroll 2
  for (int ks = 0; ks < 24; ++ks) {
    const int rl = kh * 24 + ks;             // row in K2s / block-local k
    U4 kl, khh;
    kl.u4  = *(const uint4*)(K2s + (rl << 6) + (quad << 3));
    khh.u4 = *(const uint4*)(K2s + (rl << 6) + (quad << 3) + 32);
    // v2: vt[dt][r] = v2[k][dt*16 + quad*4 + r]
    const float* vb = v2g + ((kb * 48 + rl) << 6) + (quad << 2);
    const v4f vt0 = *(const v4f*)(vb);
    const v4f vt1 = *(const v4f*)(vb + 16);
    const v4f vt2 = *(const v4f*)(vb + 32);
    const v4f vt3 = *(const v4f*)(vb + 48);

    AF af0, af1;  // B-frags of L-MFMA: (q*k2) for d-halves 0/1, col index = i = c
#pragma unroll
    for (int e = 0; e < 4; ++e) {
      af0.u[e] = pack_bf16(q0[2*e] * bf2f(kl.us[2*e]),  q0[2*e+1] * bf2f(kl.us[2*e+1]));
      af1.u[e] = pack_bf16(q1[2*e] * bf2f(khh.us[2*e]), q1[2*e+1] * bf2f(khh.us[2*e+1]));
    }

    v4f o0 = z, o1 = z, o2 = z, o3 = z;
#pragma unroll
    for (int m = 0; m < 3; ++m) {
      // SWAPPED logits: rows = k1 (j), cols = q (i); lane holds P[i=c][j=..quad*4+r]
      v4f Ca = MFMA32(k1f[2*m][0],   af0.v, z);
      Ca = MFMA32(k1f[2*m][1],   af1.v, Ca);
      v4f Cb = MFMA32(k1f[2*m+1][0], af0.v, z);
      Cb = MFMA32(k1f[2*m+1][1], af1.v, Cb);
#pragma unroll
      for (int r = 0; r < 4; ++r) { Ca[r] = EXP2F(Ca[r]); Cb[r] = EXP2F(Cb[r]); }
      sS += Ca[0] + Ca[1] + Ca[2] + Ca[3] + Cb[0] + Cb[1] + Cb[2] + Cb[3];
      AF pp;  // PV B-frag: pos e<4 -> jt-even r=e; e>=4 -> jt-odd r=e-4
      pp.u[0] = pack_bf16(Ca[0], Ca[1]);
      pp.u[1] = pack_bf16(Ca[2], Ca[3]);
      pp.u[2] = pack_bf16(Cb[0], Cb[1]);
      pp.u[3] = pack_bf16(Cb[2], Cb[3]);
      o0 = MFMA32(vf[m][0], pp.v, o0);
      o1 = MFMA32(vf[m][1], pp.v, o1);
      o2 = MFMA32(vf[m][2], pp.v, o2);
      o3 = MFMA32(vf[m][3], pp.v, o3);
    }
    acc[0] += o0 * vt0;
    acc[1] += o1 * vt1;
    acc[2] += o2 * vt2;
    acc[3] += o3 * vt3;
  }

  __syncthreads();  // reuse smem for cross-wave reduction
  float* redA = (float*)smem;              // [4][16 i][64 d]
  float* redS = (float*)smem + 4096;       // [4 wv][4 quad][16 i]

  // lane (c,quad): acc[dt][r] -> i=c, d=dt*16+quad*4+r (v4f rows contiguous)
#pragma unroll
  for (int dt = 0; dt < 4; ++dt)
    *(v4f*)(redA + wv * 1024 + (c << 6) + (dt << 4) + (quad << 2)) = acc[dt];
  redS[wv * 64 + (quad << 4) + c] = sS;
  __syncthreads();

  const int pbase = (bh * 12 + it) * 4 + kb;
  float* ap_out = accp + pbase * 1024;
  for (int idx = tid; idx < 1024; idx += 256)
    ap_out[idx] = redA[idx] + redA[1024 + idx] + redA[2048 + idx] + redA[3072 + idx];
  if (tid < 16) {
    float s = 0.f;
#pragma unroll
    for (int w = 0; w < 4; ++w)
#pragma unroll
      for (int qq = 0; qq < 4; ++qq)
        s += redS[w * 64 + qq * 16 + tid];
    Sp[pbase * 16 + tid] = s;
  }
}

// ------------------------------ Phase 3: fused norm + out GEMM -------------
// grid 48 x 256thr: blk = (bit<<1)|nh; bit -> (b, it) = 16 output rows;
// nh -> N-half (256 cols). Norm: each block normalizes its OWN 16 rows of
// accp (sum 4 kb + 1/S) into LDS as bf16 hi/lo (m-partitioned, zero
// redundancy). GEMM: A-frags from LDS, B (W_out^T hi/lo) depth-1 prefetch.
__global__ __launch_bounds__(256) void outp2_kernel(
    const float* __restrict__ wsf, const unsigned short* __restrict__ wsh,
    const float* __restrict__ bout, float* __restrict__ y) {
  __shared__ unsigned short OHs[16 * 520];
  __shared__ unsigned short OLs[16 * 520];
  const float* accp = wsf + 393216;
  const float* Sp   = wsf + 1179648;

  const int tid = threadIdx.x;
  const int nh  = blockIdx.x & 1;
  const int bit = blockIdx.x >> 1;        // 0..23
  const int b = bit / 12, it = bit % 12;
  const int m0 = b * 192 + it * 16;       // output rows m0..m0+15

  // ---- norm phase: row i = tid>>4, cols cc0..cc0+31 ----
  {
    const int i = tid >> 4, cc0 = (tid & 15) * 32;
    const int h = cc0 >> 6;               // constant within the 32-col chunk
    const int pb = ((b * 8 + h) * 12 + it) * 4;
    const float inv = 1.0f / (Sp[pb * 16 + i] + Sp[(pb + 1) * 16 + i] +
                              Sp[(pb + 2) * 16 + i] + Sp[(pb + 3) * 16 + i]);
    const float* ap = accp + pb * 1024 + (i << 6) + (cc0 & 63);
#pragma unroll
    for (int g = 0; g < 8; ++g) {
      v4f a = *(const v4f*)(ap + g * 4);
      a += *(const v4f*)(ap + 1024 + g * 4);
      a += *(const v4f*)(ap + 2048 + g * 4);
      a += *(const v4f*)(ap + 3072 + g * 4);
#pragma unroll
      for (int j = 0; j < 4; ++j) {
        const float v = a[j] * inv;
        const unsigned short hh = f2bf(v);
        OHs[i * 520 + cc0 + g * 4 + j] = hh;
        OLs[i * 520 + cc0 + g * 4 + j] = f2bf(v - bf2f(hh));
      }
    }
  }
  __syncthreads();

  // ---- GEMM phase: wave wv covers 64 cols (4 n-tiles) ----
  const int lane = tid & 63, wv = tid >> 6;
  const int c = lane & 15, q = lane >> 4;
  const int n0w = nh * 256 + wv * 64;
  const v4f z = {0.f, 0.f, 0.f, 0.f};
  v4f acc[4] = {z, z, z, z};

  const unsigned short* Bhb = wsh + WOTH_OFF;
  const unsigned short* Blb = wsh + WOTL_OFF;

  v8s cBh[4], cBl[4], nBh[4], nBl[4];
#pragma unroll
  for (int nt = 0; nt < 4; ++nt) {
    const int n = n0w + nt * 16 + c;
    cBh[nt] = *(const v8s*)(Bhb + n * 512 + (q << 3));
    cBl[nt] = *(const v8s*)(Blb + n * 512 + (q << 3));
  }

#pragma unroll 1
  for (int ks = 0; ks < 16; ++ks) {
    if (ks < 15) {
      const int o = (ks + 1) * 32 + (q << 3);
#pragma unroll
      for (int nt = 0; nt < 4; ++nt) {
        const int n = n0w + nt * 16 + c;
        nBh[nt] = *(const v8s*)(Bhb + n * 512 + o);
        nBl[nt] = *(const v8s*)(Blb + n * 512 + o);
      }
    }
    const v8s Ah = *(const v8s*)(OHs + c * 520 + ks * 32 + (q << 3));
    const v8s Al = *(const v8s*)(OLs + c * 520 + ks * 32 + (q << 3));
#pragma unroll
    for (int nt = 0; nt < 4; ++nt) {
      acc[nt] = MFMA32(Al, cBh[nt], acc[nt]);
      acc[nt] = MFMA32(Ah, cBl[nt], acc[nt]);
      acc[nt] = MFMA32(Ah, cBh[nt], acc[nt]);
    }
#pragma unroll
    for (int nt = 0; nt < 4; ++nt) { cBh[nt] = nBh[nt]; cBl[nt] = nBl[nt]; }
  }

#pragma unroll
  for (int nt = 0; nt < 4; ++nt) {
    const int n = n0w + nt * 16 + c;
    const float bv = bout[n];
#pragma unroll
    for (int r = 0; r < 4; ++r)
      y[(m0 + (q << 2) + r) * 512 + n] = acc[nt][r] + bv;
  }
}

// ------------------------------ launcher -----------------------------------
extern "C" void kernel_launch(void* const* d_in, const int* in_sizes, int n_in,
                              void* d_out, int out_size, void* d_ws, size_t ws_size,
                              hipStream_t stream) {
  const float* x    = (const float*)d_in[0];
  const float* Win  = (const float*)d_in[1];
  const float* bin  = (const float*)d_in[2];
  const float* Wout = (const float*)d_in[3];
  const float* bout = (const float*)d_in[4];

  float* wsf = (float*)d_ws;
  unsigned short* wsh = (unsigned short*)(wsf + 1191936);
  float* accp = wsf + 393216;
  float* Sp   = wsf + 1179648;

  prep_kernel<<<dim3(864), 256, 0, stream>>>(x, Win, Wout, wsh);
  proj_kernel<<<dim3(960), 64, 0, stream>>>(wsh, bin, wsf, wsh);
  attn_kernel<<<dim3(768), 256, 0, stream>>>(wsf, wsh, accp, Sp);
  outp2_kernel<<<dim3(48), 256, 0, stream>>>(wsf, wsh, bout, (float*)d_out);
}

// Round 9
// 147.626 us; speedup vs baseline: 1.0274x; 1.0274x over previous
//
#include <hip/hip_runtime.h>
#include <hip/hip_bf16.h>

// ---------------------------------------------------------------------------
// TwoSimplicialAttention  (B=2, T=192, C=512, H=8, D=64)
// R13: (a) attn back to R10's proven unroll-1 loop (R12's unroll2 neutral,
//      +20 VGPR). (b) outp2 fusion KEPT but widened: 96 blocks (16 rows x
//      128 cols each; norm phase redundant x4, L2-hit) -- R12's 48-block
//      version was latency-exposed (1 wave/SIMD on 48 CUs, +8us). GEMM B
//      loads get depth-2 prefetch (proj's proven pattern).
//      Pipeline: prep -> proj -> attn -> outp2 (4 launches).
// ---------------------------------------------------------------------------

typedef float  v4f __attribute__((ext_vector_type(4)));
typedef short  v8s __attribute__((ext_vector_type(8)));

__device__ __forceinline__ unsigned short f2bf(float f) {
  unsigned u = __float_as_uint(f);
  u += 0x7fffu + ((u >> 16) & 1u);       // RNE
  return (unsigned short)(u >> 16);
}
__device__ __forceinline__ float bf2f(unsigned short b) {
  return __uint_as_float(((unsigned)b) << 16);
}
__device__ __forceinline__ unsigned pack_bf16(float lo, float hi) {
  __hip_bfloat162 t = __float22bfloat162_rn(float2{lo, hi});
  union { __hip_bfloat162 b; unsigned u; } cv;
  cv.b = t;
  return cv.u;
}

#if __has_builtin(__builtin_amdgcn_exp2f)
#define EXP2F(x) __builtin_amdgcn_exp2f(x)
#else
#define EXP2F(x) exp2f(x)
#endif

#define MFMA32(a, b, c) __builtin_amdgcn_mfma_f32_16x16x32_bf16((a), (b), (c), 0, 0, 0)

// q scale = D^-0.5 * log2(e)
#define QSCALE 0.18033688011112042f

// ws layout, floats (wsf):
//   qs   [16][192][64]        @ 0        (q * 0.125*log2e, fp32)
//   v2p  [16][192][64]        @ 196608   (fp32, linear [k][d])
//   accp [16][12][4][16][64]  @ 393216
//   Sp   [16][12][4][16]      @ 1179648  (total fp32: 1191936)
// ws layout, ushort (wsh = wsf + 1191936):
//   k1b  [16][192][64]  @ 0
//   k2b  [16][192][64]  @ 196608
//   v1t  [16][64][192]  @ 393216   (columns PERMUTED within 32-chunks)
//   xh   [384][512]     @ 589824      xl @ 786432
//   Wth  [2560][512]    @ 983040      Wtl @ 2293760   (W_in^T, k-major)
//   Woth [512][512]     @ 3604480     Wotl @ 3866624  (W_out^T, k-major)

#define XH_OFF   589824
#define XL_OFF   786432
#define WTH_OFF  983040
#define WTL_OFF  2293760
#define WOTH_OFF 3604480
#define WOTL_OFF 3866624

// V1 column position for j-offset t within a 32-chunk (R10 ordering):
//   quad = (t>>2)&3, hi = (t>>4)&1, r = t&3  ->  p = quad*8 + hi*4 + r
// inverse: t = ((p>>3)&3)<<2 | ((p>>2)&1)<<4 | (p&3)
__device__ __forceinline__ int v1perm_inv(int p) {
  return (((p >> 3) & 3) << 2) | (((p >> 2) & 1) << 4) | (p & 3);
}

// ------------------------------ Phase 0: prep ------------------------------
// grid 864: [0,640) W_in transpose+split (64n x 32k tiles), [640,768) W_out,
// [768,864) x hi/lo split. W goes through LDS so global writes are dense.
__global__ __launch_bounds__(256) void prep_kernel(
    const float* __restrict__ x, const float* __restrict__ Win,
    const float* __restrict__ Wout, unsigned short* __restrict__ wsh) {
  __shared__ float tile[32 * 65];
  const int bi = blockIdx.x, t = threadIdx.x;
  if (bi < 768) {
    const float* W; unsigned short *Th, *Tl; int R, n0, k0;
    if (bi < 640) {
      W = Win; Th = wsh + WTH_OFF; Tl = wsh + WTL_OFF; R = 2560;
      n0 = (bi % 40) << 6; k0 = (bi / 40) << 5;
    } else {
      const int idx = bi - 640;
      W = Wout; Th = wsh + WOTH_OFF; Tl = wsh + WOTL_OFF; R = 512;
      n0 = (idx & 7) << 6; k0 = (idx >> 3) << 5;
    }
    // phase 1: coalesced reads -> LDS [k][n] (pad 65)
    const int n = t & 63, kq = (t >> 6) * 8;
#pragma unroll
    for (int j = 0; j < 8; ++j)
      tile[(kq + j) * 65 + n] = W[(k0 + kq + j) * R + n0 + n];
    __syncthreads();
    // phase 2: k-contig hi/lo writes (dense 64B lines)
    const int n2 = t >> 2, ks = (t & 3) * 8;
    union { uint4 u; unsigned short us[8]; } ph, pl;
#pragma unroll
    for (int j = 0; j < 8; ++j) {
      const float v = tile[(ks + j) * 65 + n2];
      const unsigned short h = f2bf(v);
      ph.us[j] = h;
      pl.us[j] = f2bf(v - bf2f(h));
    }
    *(uint4*)(Th + (n0 + n2) * 512 + k0 + ks) = ph.u;
    *(uint4*)(Tl + (n0 + n2) * 512 + k0 + ks) = pl.u;
  } else {
    const int flat = ((bi - 768) * 256 + t) * 8;
    const v4f v0 = *(const v4f*)(x + flat);
    const v4f v1 = *(const v4f*)(x + flat + 4);
    union { uint4 u; unsigned short us[8]; } ph, pl;
#pragma unroll
    for (int j = 0; j < 4; ++j) {
      unsigned short h = f2bf(v0[j]);
      ph.us[j] = h; pl.us[j] = f2bf(v0[j] - bf2f(h));
      h = f2bf(v1[j]);
      ph.us[4 + j] = h; pl.us[4 + j] = f2bf(v1[j] - bf2f(h));
    }
    *(uint4*)(wsh + XH_OFF + flat) = ph.u;
    *(uint4*)(wsh + XL_OFF + flat) = pl.u;
  }
}

// ------------------------------ Phase 1: proj (bf16x3 MFMA) ----------------
// grid 960 x 64thr: 1 wave/block, 32x32 C-tile, prefetch depth 2.
// Epilogue: LDS tile -> coalesced per-which stores (tile-constant which/bh).
__global__ __launch_bounds__(64) void proj_kernel(
    const unsigned short* __restrict__ wsh, const float* __restrict__ bin,
    float* __restrict__ wsf, unsigned short* __restrict__ wshd) {
  __shared__ float tile[32 * 33];
  const int lane = threadIdx.x;
  const int c = lane & 15, q = lane >> 4;
  const int bm = blockIdx.x % 12, bn = blockIdx.x / 12;

  const unsigned short* base[8];
  base[0] = wsh + XH_OFF + (bm * 32 + c) * 512 + (q << 3);
  base[1] = base[0] + 16 * 512;
  base[2] = wsh + XL_OFF + (bm * 32 + c) * 512 + (q << 3);
  base[3] = base[2] + 16 * 512;
  base[4] = wsh + WTH_OFF + (bn * 32 + c) * 512 + (q << 3);
  base[5] = base[4] + 16 * 512;
  base[6] = wsh + WTL_OFF + (bn * 32 + c) * 512 + (q << 3);
  base[7] = base[6] + 16 * 512;

  const v4f z = {0.f, 0.f, 0.f, 0.f};
  v4f a00 = z, a01 = z, a10 = z, a11 = z;

  v8s cur[8], nxt[8];
#pragma unroll
  for (int i = 0; i < 8; ++i) cur[i] = *(const v8s*)(base[i]);
#pragma unroll
  for (int i = 0; i < 8; ++i) nxt[i] = *(const v8s*)(base[i] + 32);

#pragma unroll 1
  for (int ks = 0; ks < 16; ++ks) {
    v8s nx2[8];
    if (ks < 14) {
      const int o = (ks + 2) * 32;
#pragma unroll
      for (int i = 0; i < 8; ++i) nx2[i] = *(const v8s*)(base[i] + o);
    }
    // Ah0,Ah1,Al0,Al1 = cur[0..3]; Bh0,Bh1,Bl0,Bl1 = cur[4..7]
    a00 = MFMA32(cur[2], cur[4], a00); a00 = MFMA32(cur[0], cur[6], a00); a00 = MFMA32(cur[0], cur[4], a00);
    a01 = MFMA32(cur[2], cur[5], a01); a01 = MFMA32(cur[0], cur[7], a01); a01 = MFMA32(cur[0], cur[5], a01);
    a10 = MFMA32(cur[3], cur[4], a10); a10 = MFMA32(cur[1], cur[6], a10); a10 = MFMA32(cur[1], cur[4], a10);
    a11 = MFMA32(cur[3], cur[5], a11); a11 = MFMA32(cur[1], cur[7], a11); a11 = MFMA32(cur[1], cur[5], a11);
#pragma unroll
    for (int i = 0; i < 8; ++i) { cur[i] = nxt[i]; nxt[i] = nx2[i]; }
  }

  // ---- epilogue via LDS tile (coalesced stores) ----
  const int n0 = bn * 32;
  const int which = n0 >> 9;
  const int h  = (n0 & 511) >> 6;
  const int d0 = n0 & 63;                 // 0 or 32
  const int b  = (bm >= 6) ? 1 : 0;
  const int bh = b * 8 + h;
  const int tt0 = (bm - b * 6) * 32;

  v4f accs[2][2] = {{a00, a01}, {a10, a11}};
#pragma unroll
  for (int mt = 0; mt < 2; ++mt)
#pragma unroll
    for (int nt = 0; nt < 2; ++nt) {
      const float bv = bin[n0 + nt * 16 + c];
#pragma unroll
      for (int r = 0; r < 4; ++r)
        tile[(mt * 16 + (q << 2) + r) * 33 + nt * 16 + c] = accs[mt][nt][r] + bv;
    }
  __syncthreads();

  const int rr = lane >> 1, cc0 = (lane & 1) * 16;
  if (which == 0 || which == 4) {
    float* out = wsf + (which == 4 ? 196608 : 0) + ((bh * 192 + tt0 + rr) << 6) + d0 + cc0;
    const float s = (which == 0) ? QSCALE : 1.0f;
#pragma unroll
    for (int i = 0; i < 16; i += 4) {
      v4f v;
#pragma unroll
      for (int j = 0; j < 4; ++j) v[j] = tile[rr * 33 + cc0 + i + j] * s;
      *(v4f*)(out + i) = v;
    }
  } else if (which == 1 || which == 3) {
    unsigned short* out = wshd + (which == 3 ? 196608 : 0) + ((bh * 192 + tt0 + rr) << 6) + d0 + cc0;
#pragma unroll
    for (int hf = 0; hf < 2; ++hf) {
      union { uint4 u; unsigned short us[8]; } pk;
#pragma unroll
      for (int j = 0; j < 8; ++j) pk.us[j] = f2bf(tile[rr * 33 + cc0 + hf * 8 + j]);
      *(uint4*)(out + hf * 8) = pk.u;
    }
  } else {  // which == 2: v1t, transposed + permuted (column reads from LDS)
    const int dd = rr, p0 = cc0;
    unsigned short* out = wshd + 393216 + ((bh << 6) + d0 + dd) * 192 + tt0 + p0;
#pragma unroll
    for (int hf = 0; hf < 2; ++hf) {
      union { uint4 u; unsigned short us[8]; } pk;
#pragma unroll
      for (int j = 0; j < 8; ++j) {
        const int p = p0 + hf * 8 + j;
        pk.us[j] = f2bf(tile[v1perm_inv(p) * 33 + dd]);
      }
      *(uint4*)(out + hf * 8) = pk.u;
    }
  }
}

// ------------------------------ Phase 2: attention -------------------------
// grid = 16(bh)*12(i)*4(ksplit) = 768 blocks, 256 thr (4 waves).
// R10 structure (proven 51.0us): wave (jh,kh) does 6 jt x 24 ksteps; P stays
// in registers via operand-swapped MFMAs; per-m interleaved body.
__global__ __launch_bounds__(256, 2) void attn_kernel(
    const float* __restrict__ wsf, const unsigned short* __restrict__ wsh,
    float* __restrict__ accp, float* __restrict__ Sp) {
  __shared__ char smem[17408];
  unsigned short* K2s = (unsigned short*)smem;            // [48][64]

  const int tid  = threadIdx.x;
  const int wv   = tid >> 6;
  const int lane = tid & 63;
  const int c    = lane & 15;
  const int quad = lane >> 4;
  const int jh   = wv & 1;
  const int kh   = wv >> 1;

  const int bb = blockIdx.x;
  const int kb = bb & 3;
  const int it = (bb >> 2) % 12;
  const int bh = bb / 48;

  const unsigned short* k1g = wsh + bh * 192 * 64;
  const unsigned short* v1g = wsh + 393216 + bh * 64 * 192;
  const unsigned short* k2g = wsh + 196608 + bh * 192 * 64;
  const float*          v2g = wsf + 196608 + bh * 12288;   // [192][64] f32

  // stage this block's 48 k2 rows (only LDS staging left)
  for (int idx = tid; idx < 384; idx += 256) {
    const int r = idx >> 3, c8 = (idx & 7) * 8;
    *(uint4*)(K2s + r * 64 + c8) = *(const uint4*)(k2g + (kb * 48 + r) * 64 + c8);
  }

  // K1 A-frags (this wave's 6 jt): frag[j][h] = K1[(jh*6+j)*16+c][h*32+quad*8..+8]
  v8s k1f[6][2];
#pragma unroll
  for (int j = 0; j < 6; ++j) {
    const unsigned short* kp = k1g + (((jh * 6 + j) * 16 + c) << 6) + (quad << 3);
    k1f[j][0] = *(const v8s*)(kp);
    k1f[j][1] = *(const v8s*)(kp + 32);
  }

  // PV A-frags (kstep-invariant): vf[m][dt] = V1t[d=dt*16+c][chunk(jh*3+m), pos quad*8..+8]
  v8s vf[3][4];
#pragma unroll
  for (int m = 0; m < 3; ++m)
#pragma unroll
    for (int dt = 0; dt < 4; ++dt)
      vf[m][dt] = *(const v8s*)(v1g + (dt * 16 + c) * 192 + ((jh * 3 + m) << 5) + (quad << 3));

  // q rows (fp32, pre-scaled): i = it*16+c, d = quad*8+e (+32)
  const float* qg = wsf + ((bh * 192 + it * 16 + c) << 6) + (quad << 3);
  float q0[8], q1[8];
  {
    v4f qa = *(const v4f*)(qg), qb = *(const v4f*)(qg + 4);
    v4f qc = *(const v4f*)(qg + 32), qd = *(const v4f*)(qg + 36);
#pragma unroll
    for (int e = 0; e < 4; ++e) {
      q0[e] = qa[e]; q0[4 + e] = qb[e];
      q1[e] = qc[e]; q1[4 + e] = qd[e];
    }
  }
  __syncthreads();   // K2s staged; no barriers until epilogue

  const v4f z = {0.f, 0.f, 0.f, 0.f};
  v4f acc[4] = {z, z, z, z};
  float sS = 0.f;

  union U4 { uint4 u4; unsigned short us[8]; };
  union AF { v8s v; unsigned u[4]; };

#pragma unroll 1
  for (int ks = 0; ks < 24; ++ks) {
    const int rl = kh * 24 + ks;             // row in K2s / block-local k
    U4 kl, khh;
    kl.u4  = *(const uint4*)(K2s + (rl << 6) + (quad << 3));
    khh.u4 = *(const uint4*)(K2s + (rl << 6) + (quad << 3) + 32);
    // v2: vt[dt][r] = v2[k][dt*16 + quad*4 + r]
    const float* vb = v2g + ((kb * 48 + rl) << 6) + (quad << 2);
    const v4f vt0 = *(const v4f*)(vb);
    const v4f vt1 = *(const v4f*)(vb + 16);
    const v4f vt2 = *(const v4f*)(vb + 32);
    const v4f vt3 = *(const v4f*)(vb + 48);

    AF af0, af1;  // B-frags of L-MFMA: (q*k2) for d-halves 0/1, col index = i = c
#pragma unroll
    for (int e = 0; e < 4; ++e) {
      af0.u[e] = pack_bf16(q0[2*e] * bf2f(kl.us[2*e]),  q0[2*e+1] * bf2f(kl.us[2*e+1]));
      af1.u[e] = pack_bf16(q1[2*e] * bf2f(khh.us[2*e]), q1[2*e+1] * bf2f(khh.us[2*e+1]));
    }

    v4f o0 = z, o1 = z, o2 = z, o3 = z;
#pragma unroll
    for (int m = 0; m < 3; ++m) {
      // SWAPPED logits: rows = k1 (j), cols = q (i); lane holds P[i=c][j=..quad*4+r]
      v4f Ca = MFMA32(k1f[2*m][0],   af0.v, z);
      Ca = MFMA32(k1f[2*m][1],   af1.v, Ca);
      v4f Cb = MFMA32(k1f[2*m+1][0], af0.v, z);
      Cb = MFMA32(k1f[2*m+1][1], af1.v, Cb);
#pragma unroll
      for (int r = 0; r < 4; ++r) { Ca[r] = EXP2F(Ca[r]); Cb[r] = EXP2F(Cb[r]); }
      sS += Ca[0] + Ca[1] + Ca[2] + Ca[3] + Cb[0] + Cb[1] + Cb[2] + Cb[3];
      AF pp;  // PV B-frag: pos e<4 -> jt-even r=e; e>=4 -> jt-odd r=e-4
      pp.u[0] = pack_bf16(Ca[0], Ca[1]);
      pp.u[1] = pack_bf16(Ca[2], Ca[3]);
      pp.u[2] = pack_bf16(Cb[0], Cb[1]);
      pp.u[3] = pack_bf16(Cb[2], Cb[3]);
      o0 = MFMA32(vf[m][0], pp.v, o0);
      o1 = MFMA32(vf[m][1], pp.v, o1);
      o2 = MFMA32(vf[m][2], pp.v, o2);
      o3 = MFMA32(vf[m][3], pp.v, o3);
    }
    acc[0] += o0 * vt0;
    acc[1] += o1 * vt1;
    acc[2] += o2 * vt2;
    acc[3] += o3 * vt3;
  }

  __syncthreads();  // reuse smem for cross-wave reduction
  float* redA = (float*)smem;              // [4][16 i][64 d]
  float* redS = (float*)smem + 4096;       // [4 wv][4 quad][16 i]

  // lane (c,quad): acc[dt][r] -> i=c, d=dt*16+quad*4+r (v4f rows contiguous)
#pragma unroll
  for (int dt = 0; dt < 4; ++dt)
    *(v4f*)(redA + wv * 1024 + (c << 6) + (dt << 4) + (quad << 2)) = acc[dt];
  redS[wv * 64 + (quad << 4) + c] = sS;
  __syncthreads();

  const int pbase = (bh * 12 + it) * 4 + kb;
  float* ap_out = accp + pbase * 1024;
  for (int idx = tid; idx < 1024; idx += 256)
    ap_out[idx] = redA[idx] + redA[1024 + idx] + redA[2048 + idx] + redA[3072 + idx];
  if (tid < 16) {
    float s = 0.f;
#pragma unroll
    for (int w = 0; w < 4; ++w)
#pragma unroll
      for (int qq = 0; qq < 4; ++qq)
        s += redS[w * 64 + qq * 16 + tid];
    Sp[pbase * 16 + tid] = s;
  }
}

// ------------------------------ Phase 3: fused norm + out GEMM -------------
// grid 96 x 256thr: blk = bit*4 + nq; bit -> (b, it) = 16 output rows;
// nq -> 128-col slab. Norm: block normalizes its 16 rows of accp into LDS
// as bf16 hi/lo (redundant x4 across nq, L2-hit -- buys 2x grid parallelism
// vs the 48-block R12 version which was latency-exposed). GEMM: wave = 32
// cols (2 n-tiles), B (W_out^T hi/lo) depth-2 prefetch, A-frags from LDS.
__global__ __launch_bounds__(256) void outp2_kernel(
    const float* __restrict__ wsf, const unsigned short* __restrict__ wsh,
    const float* __restrict__ bout, float* __restrict__ y) {
  __shared__ unsigned short OHs[16 * 520];
  __shared__ unsigned short OLs[16 * 520];
  const float* accp = wsf + 393216;
  const float* Sp   = wsf + 1179648;

  const int tid = threadIdx.x;
  const int nq  = blockIdx.x & 3;
  const int bit = blockIdx.x >> 2;        // 0..23
  const int b = bit / 12, it = bit % 12;
  const int m0 = b * 192 + it * 16;       // output rows m0..m0+15

  // ---- norm phase: row i = tid>>4, cols cc0..cc0+31 ----
  {
    const int i = tid >> 4, cc0 = (tid & 15) * 32;
    const int h = cc0 >> 6;               // constant within the 32-col chunk
    const int pb = ((b * 8 + h) * 12 + it) * 4;
    const float inv = 1.0f / (Sp[pb * 16 + i] + Sp[(pb + 1) * 16 + i] +
                              Sp[(pb + 2) * 16 + i] + Sp[(pb + 3) * 16 + i]);
    const float* ap = accp + pb * 1024 + (i << 6) + (cc0 & 63);
#pragma unroll
    for (int g = 0; g < 8; ++g) {
      v4f a = *(const v4f*)(ap + g * 4);
      a += *(const v4f*)(ap + 1024 + g * 4);
      a += *(const v4f*)(ap + 2048 + g * 4);
      a += *(const v4f*)(ap + 3072 + g * 4);
#pragma unroll
      for (int j = 0; j < 4; ++j) {
        const float v = a[j] * inv;
        const unsigned short hh = f2bf(v);
        OHs[i * 520 + cc0 + g * 4 + j] = hh;
        OLs[i * 520 + cc0 + g * 4 + j] = f2bf(v - bf2f(hh));
      }
    }
  }
  __syncthreads();

  // ---- GEMM phase: wave wv covers 32 cols (2 n-tiles) ----
  const int lane = tid & 63, wv = tid >> 6;
  const int c = lane & 15, q = lane >> 4;
  const int n0w = nq * 128 + wv * 32;
  const v4f z = {0.f, 0.f, 0.f, 0.f};
  v4f acc[2] = {z, z};

  const unsigned short* Bhb = wsh + WOTH_OFF;
  const unsigned short* Blb = wsh + WOTL_OFF;

  // cB/nB layout: [nt*2 + 0]=Bh, [nt*2 + 1]=Bl
  v8s cB[4], nB[4];
#pragma unroll
  for (int nt = 0; nt < 2; ++nt) {
    const int n = n0w + nt * 16 + c;
    cB[nt * 2]     = *(const v8s*)(Bhb + n * 512 + (q << 3));
    cB[nt * 2 + 1] = *(const v8s*)(Blb + n * 512 + (q << 3));
    nB[nt * 2]     = *(const v8s*)(Bhb + n * 512 + 32 + (q << 3));
    nB[nt * 2 + 1] = *(const v8s*)(Blb + n * 512 + 32 + (q << 3));
  }

#pragma unroll 1
  for (int ks = 0; ks < 16; ++ks) {
    v8s x2[4];
    if (ks < 14) {
      const int o = (ks + 2) * 32 + (q << 3);
#pragma unroll
      for (int nt = 0; nt < 2; ++nt) {
        const int n = n0w + nt * 16 + c;
        x2[nt * 2]     = *(const v8s*)(Bhb + n * 512 + o);
        x2[nt * 2 + 1] = *(const v8s*)(Blb + n * 512 + o);
      }
    }
    const v8s Ah = *(const v8s*)(OHs + c * 520 + ks * 32 + (q << 3));
    const v8s Al = *(const v8s*)(OLs + c * 520 + ks * 32 + (q << 3));
#pragma unroll
    for (int nt = 0; nt < 2; ++nt) {
      acc[nt] = MFMA32(Al, cB[nt * 2],     acc[nt]);
      acc[nt] = MFMA32(Ah, cB[nt * 2 + 1], acc[nt]);
      acc[nt] = MFMA32(Ah, cB[nt * 2],     acc[nt]);
    }
#pragma unroll
    for (int i2 = 0; i2 < 4; ++i2) { cB[i2] = nB[i2]; nB[i2] = x2[i2]; }
  }

#pragma unroll
  for (int nt = 0; nt < 2; ++nt) {
    const int n = n0w + nt * 16 + c;
    const float bv = bout[n];
#pragma unroll
    for (int r = 0; r < 4; ++r)
      y[(m0 + (q << 2) + r) * 512 + n] = acc[nt][r] + bv;
  }
}

// ------------------------------ launcher -----------------------------------
extern "C" void kernel_launch(void* const* d_in, const int* in_sizes, int n_in,
                              void* d_out, int out_size, void* d_ws, size_t ws_size,
                              hipStream_t stream) {
  const float* x    = (const float*)d_in[0];
  const float* Win  = (const float*)d_in[1];
  const float* bin  = (const float*)d_in[2];
  const float* Wout = (const float*)d_in[3];
  const float* bout = (const float*)d_in[4];

  float* wsf = (float*)d_ws;
  unsigned short* wsh = (unsigned short*)(wsf + 1191936);
  float* accp = wsf + 393216;
  float* Sp   = wsf + 1179648;

  prep_kernel<<<dim3(864), 256, 0, stream>>>(x, Win, Wout, wsh);
  proj_kernel<<<dim3(960), 64, 0, stream>>>(wsh, bin, wsf, wsh);
  attn_kernel<<<dim3(768), 256, 0, stream>>>(wsf, wsh, accp, Sp);
  outp2_kernel<<<dim3(96), 256, 0, stream>>>(wsf, wsh, bout, (float*)d_out);
}

// Round 10
// 145.073 us; speedup vs baseline: 1.0455x; 1.0176x over previous
//
#include <hip/hip_runtime.h>
#include <hip/hip_bf16.h>

// ---------------------------------------------------------------------------
// TwoSimplicialAttention  (B=2, T=192, C=512, H=8, D=64)
// R14: attn register diet: vf[3][4] (48 VGPRs, kstep-invariant PV A-frags)
//      demoted to LDS (V1s [64][200], pad->2-way bank alias = free). Unified
//      VGPR+AGPR/wave ~200 -> ~152 => 3 waves/SIMD (was 2) => grid 768 =
//      3 blocks/CU fully resident. +12 ds_read_b128/kstep (~6% issue) traded
//      for +50% latency hiding. Everything else = R13.
// ---------------------------------------------------------------------------

typedef float  v4f __attribute__((ext_vector_type(4)));
typedef short  v8s __attribute__((ext_vector_type(8)));

__device__ __forceinline__ unsigned short f2bf(float f) {
  unsigned u = __float_as_uint(f);
  u += 0x7fffu + ((u >> 16) & 1u);       // RNE
  return (unsigned short)(u >> 16);
}
__device__ __forceinline__ float bf2f(unsigned short b) {
  return __uint_as_float(((unsigned)b) << 16);
}
__device__ __forceinline__ unsigned pack_bf16(float lo, float hi) {
  __hip_bfloat162 t = __float22bfloat162_rn(float2{lo, hi});
  union { __hip_bfloat162 b; unsigned u; } cv;
  cv.b = t;
  return cv.u;
}

#if __has_builtin(__builtin_amdgcn_exp2f)
#define EXP2F(x) __builtin_amdgcn_exp2f(x)
#else
#define EXP2F(x) exp2f(x)
#endif

#define MFMA32(a, b, c) __builtin_amdgcn_mfma_f32_16x16x32_bf16((a), (b), (c), 0, 0, 0)

// q scale = D^-0.5 * log2(e)
#define QSCALE 0.18033688011112042f

// ws layout, floats (wsf):
//   qs   [16][192][64]        @ 0        (q * 0.125*log2e, fp32)
//   v2p  [16][192][64]        @ 196608   (fp32, linear [k][d])
//   accp [16][12][4][16][64]  @ 393216
//   Sp   [16][12][4][16]      @ 1179648  (total fp32: 1191936)
// ws layout, ushort (wsh = wsf + 1191936):
//   k1b  [16][192][64]  @ 0
//   k2b  [16][192][64]  @ 196608
//   v1t  [16][64][192]  @ 393216   (columns PERMUTED within 32-chunks)
//   xh   [384][512]     @ 589824      xl @ 786432
//   Wth  [2560][512]    @ 983040      Wtl @ 2293760   (W_in^T, k-major)
//   Woth [512][512]     @ 3604480     Wotl @ 3866624  (W_out^T, k-major)

#define XH_OFF   589824
#define XL_OFF   786432
#define WTH_OFF  983040
#define WTL_OFF  2293760
#define WOTH_OFF 3604480
#define WOTL_OFF 3866624

// V1 column position for j-offset t within a 32-chunk (R10 ordering):
//   quad = (t>>2)&3, hi = (t>>4)&1, r = t&3  ->  p = quad*8 + hi*4 + r
// inverse: t = ((p>>3)&3)<<2 | ((p>>2)&1)<<4 | (p&3)
__device__ __forceinline__ int v1perm_inv(int p) {
  return (((p >> 3) & 3) << 2) | (((p >> 2) & 1) << 4) | (p & 3);
}

// ------------------------------ Phase 0: prep ------------------------------
// grid 864: [0,640) W_in transpose+split (64n x 32k tiles), [640,768) W_out,
// [768,864) x hi/lo split. W goes through LDS so global writes are dense.
__global__ __launch_bounds__(256) void prep_kernel(
    const float* __restrict__ x, const float* __restrict__ Win,
    const float* __restrict__ Wout, unsigned short* __restrict__ wsh) {
  __shared__ float tile[32 * 65];
  const int bi = blockIdx.x, t = threadIdx.x;
  if (bi < 768) {
    const float* W; unsigned short *Th, *Tl; int R, n0, k0;
    if (bi < 640) {
      W = Win; Th = wsh + WTH_OFF; Tl = wsh + WTL_OFF; R = 2560;
      n0 = (bi % 40) << 6; k0 = (bi / 40) << 5;
    } else {
      const int idx = bi - 640;
      W = Wout; Th = wsh + WOTH_OFF; Tl = wsh + WOTL_OFF; R = 512;
      n0 = (idx & 7) << 6; k0 = (idx >> 3) << 5;
    }
    // phase 1: coalesced reads -> LDS [k][n] (pad 65)
    const int n = t & 63, kq = (t >> 6) * 8;
#pragma unroll
    for (int j = 0; j < 8; ++j)
      tile[(kq + j) * 65 + n] = W[(k0 + kq + j) * R + n0 + n];
    __syncthreads();
    // phase 2: k-contig hi/lo writes (dense 64B lines)
    const int n2 = t >> 2, ks = (t & 3) * 8;
    union { uint4 u; unsigned short us[8]; } ph, pl;
#pragma unroll
    for (int j = 0; j < 8; ++j) {
      const float v = tile[(ks + j) * 65 + n2];
      const unsigned short h = f2bf(v);
      ph.us[j] = h;
      pl.us[j] = f2bf(v - bf2f(h));
    }
    *(uint4*)(Th + (n0 + n2) * 512 + k0 + ks) = ph.u;
    *(uint4*)(Tl + (n0 + n2) * 512 + k0 + ks) = pl.u;
  } else {
    const int flat = ((bi - 768) * 256 + t) * 8;
    const v4f v0 = *(const v4f*)(x + flat);
    const v4f v1 = *(const v4f*)(x + flat + 4);
    union { uint4 u; unsigned short us[8]; } ph, pl;
#pragma unroll
    for (int j = 0; j < 4; ++j) {
      unsigned short h = f2bf(v0[j]);
      ph.us[j] = h; pl.us[j] = f2bf(v0[j] - bf2f(h));
      h = f2bf(v1[j]);
      ph.us[4 + j] = h; pl.us[4 + j] = f2bf(v1[j] - bf2f(h));
    }
    *(uint4*)(wsh + XH_OFF + flat) = ph.u;
    *(uint4*)(wsh + XL_OFF + flat) = pl.u;
  }
}

// ------------------------------ Phase 1: proj (bf16x3 MFMA) ----------------
// grid 960 x 64thr: 1 wave/block, 32x32 C-tile, prefetch depth 2.
// Epilogue: LDS tile -> coalesced per-which stores (tile-constant which/bh).
__global__ __launch_bounds__(64) void proj_kernel(
    const unsigned short* __restrict__ wsh, const float* __restrict__ bin,
    float* __restrict__ wsf, unsigned short* __restrict__ wshd) {
  __shared__ float tile[32 * 33];
  const int lane = threadIdx.x;
  const int c = lane & 15, q = lane >> 4;
  const int bm = blockIdx.x % 12, bn = blockIdx.x / 12;

  const unsigned short* base[8];
  base[0] = wsh + XH_OFF + (bm * 32 + c) * 512 + (q << 3);
  base[1] = base[0] + 16 * 512;
  base[2] = wsh + XL_OFF + (bm * 32 + c) * 512 + (q << 3);
  base[3] = base[2] + 16 * 512;
  base[4] = wsh + WTH_OFF + (bn * 32 + c) * 512 + (q << 3);
  base[5] = base[4] + 16 * 512;
  base[6] = wsh + WTL_OFF + (bn * 32 + c) * 512 + (q << 3);
  base[7] = base[6] + 16 * 512;

  const v4f z = {0.f, 0.f, 0.f, 0.f};
  v4f a00 = z, a01 = z, a10 = z, a11 = z;

  v8s cur[8], nxt[8];
#pragma unroll
  for (int i = 0; i < 8; ++i) cur[i] = *(const v8s*)(base[i]);
#pragma unroll
  for (int i = 0; i < 8; ++i) nxt[i] = *(const v8s*)(base[i] + 32);

#pragma unroll 1
  for (int ks = 0; ks < 16; ++ks) {
    v8s nx2[8];
    if (ks < 14) {
      const int o = (ks + 2) * 32;
#pragma unroll
      for (int i = 0; i < 8; ++i) nx2[i] = *(const v8s*)(base[i] + o);
    }
    // Ah0,Ah1,Al0,Al1 = cur[0..3]; Bh0,Bh1,Bl0,Bl1 = cur[4..7]
    a00 = MFMA32(cur[2], cur[4], a00); a00 = MFMA32(cur[0], cur[6], a00); a00 = MFMA32(cur[0], cur[4], a00);
    a01 = MFMA32(cur[2], cur[5], a01); a01 = MFMA32(cur[0], cur[7], a01); a01 = MFMA32(cur[0], cur[5], a01);
    a10 = MFMA32(cur[3], cur[4], a10); a10 = MFMA32(cur[1], cur[6], a10); a10 = MFMA32(cur[1], cur[4], a10);
    a11 = MFMA32(cur[3], cur[5], a11); a11 = MFMA32(cur[1], cur[7], a11); a11 = MFMA32(cur[1], cur[5], a11);
#pragma unroll
    for (int i = 0; i < 8; ++i) { cur[i] = nxt[i]; nxt[i] = nx2[i]; }
  }

  // ---- epilogue via LDS tile (coalesced stores) ----
  const int n0 = bn * 32;
  const int which = n0 >> 9;
  const int h  = (n0 & 511) >> 6;
  const int d0 = n0 & 63;                 // 0 or 32
  const int b  = (bm >= 6) ? 1 : 0;
  const int bh = b * 8 + h;
  const int tt0 = (bm - b * 6) * 32;

  v4f accs[2][2] = {{a00, a01}, {a10, a11}};
#pragma unroll
  for (int mt = 0; mt < 2; ++mt)
#pragma unroll
    for (int nt = 0; nt < 2; ++nt) {
      const float bv = bin[n0 + nt * 16 + c];
#pragma unroll
      for (int r = 0; r < 4; ++r)
        tile[(mt * 16 + (q << 2) + r) * 33 + nt * 16 + c] = accs[mt][nt][r] + bv;
    }
  __syncthreads();

  const int rr = lane >> 1, cc0 = (lane & 1) * 16;
  if (which == 0 || which == 4) {
    float* out = wsf + (which == 4 ? 196608 : 0) + ((bh * 192 + tt0 + rr) << 6) + d0 + cc0;
    const float s = (which == 0) ? QSCALE : 1.0f;
#pragma unroll
    for (int i = 0; i < 16; i += 4) {
      v4f v;
#pragma unroll
      for (int j = 0; j < 4; ++j) v[j] = tile[rr * 33 + cc0 + i + j] * s;
      *(v4f*)(out + i) = v;
    }
  } else if (which == 1 || which == 3) {
    unsigned short* out = wshd + (which == 3 ? 196608 : 0) + ((bh * 192 + tt0 + rr) << 6) + d0 + cc0;
#pragma unroll
    for (int hf = 0; hf < 2; ++hf) {
      union { uint4 u; unsigned short us[8]; } pk;
#pragma unroll
      for (int j = 0; j < 8; ++j) pk.us[j] = f2bf(tile[rr * 33 + cc0 + hf * 8 + j]);
      *(uint4*)(out + hf * 8) = pk.u;
    }
  } else {  // which == 2: v1t, transposed + permuted (column reads from LDS)
    const int dd = rr, p0 = cc0;
    unsigned short* out = wshd + 393216 + ((bh << 6) + d0 + dd) * 192 + tt0 + p0;
#pragma unroll
    for (int hf = 0; hf < 2; ++hf) {
      union { uint4 u; unsigned short us[8]; } pk;
#pragma unroll
      for (int j = 0; j < 8; ++j) {
        const int p = p0 + hf * 8 + j;
        pk.us[j] = f2bf(tile[v1perm_inv(p) * 33 + dd]);
      }
      *(uint4*)(out + hf * 8) = pk.u;
    }
  }
}

// ------------------------------ Phase 2: attention -------------------------
// grid = 16(bh)*12(i)*4(ksplit) = 768 blocks, 256 thr (4 waves).
// R10 loop structure; vf demoted to LDS (V1s, stride 200) to cut 48 regs:
// unified VGPR+AGPR ~152/wave => 3 waves/SIMD, grid fully resident.
__global__ __launch_bounds__(256, 2) void attn_kernel(
    const float* __restrict__ wsf, const unsigned short* __restrict__ wsh,
    float* __restrict__ accp, float* __restrict__ Sp) {
  __shared__ char smem[31744];
  unsigned short* V1s = (unsigned short*)smem;            // [64][200]
  unsigned short* K2s = (unsigned short*)(smem + 25600);  // [48][64]

  const int tid  = threadIdx.x;
  const int wv   = tid >> 6;
  const int lane = tid & 63;
  const int c    = lane & 15;
  const int quad = lane >> 4;
  const int jh   = wv & 1;
  const int kh   = wv >> 1;

  const int bb = blockIdx.x;
  const int kb = bb & 3;
  const int it = (bb >> 2) % 12;
  const int bh = bb / 48;

  const unsigned short* k1g = wsh + bh * 192 * 64;
  const unsigned short* v1g = wsh + 393216 + bh * 64 * 192;
  const unsigned short* k2g = wsh + 196608 + bh * 192 * 64;
  const float*          v2g = wsf + 196608 + bh * 12288;   // [192][64] f32

  // stage V1^T panel (rows d=0..63, cols j, stride 200) + this kb's 48 k2 rows
  for (int idx = tid; idx < 1920; idx += 256) {
    if (idx < 1536) {
      const int r = idx / 24, c8 = (idx % 24) * 8;
      *(uint4*)(V1s + r * 200 + c8) = *(const uint4*)(v1g + r * 192 + c8);
    } else {
      const int j = idx - 1536;
      const int r = j >> 3, c8 = (j & 7) * 8;
      *(uint4*)(K2s + r * 64 + c8) = *(const uint4*)(k2g + (kb * 48 + r) * 64 + c8);
    }
  }

  // K1 A-frags (this wave's 6 jt): frag[j][h] = K1[(jh*6+j)*16+c][h*32+quad*8..+8]
  v8s k1f[6][2];
#pragma unroll
  for (int j = 0; j < 6; ++j) {
    const unsigned short* kp = k1g + (((jh * 6 + j) * 16 + c) << 6) + (quad << 3);
    k1f[j][0] = *(const v8s*)(kp);
    k1f[j][1] = *(const v8s*)(kp + 32);
  }

  // q rows (fp32, pre-scaled): i = it*16+c, d = quad*8+e (+32)
  const float* qg = wsf + ((bh * 192 + it * 16 + c) << 6) + (quad << 3);
  float q0[8], q1[8];
  {
    v4f qa = *(const v4f*)(qg), qb = *(const v4f*)(qg + 4);
    v4f qc = *(const v4f*)(qg + 32), qd = *(const v4f*)(qg + 36);
#pragma unroll
    for (int e = 0; e < 4; ++e) {
      q0[e] = qa[e]; q0[4 + e] = qb[e];
      q1[e] = qc[e]; q1[4 + e] = qd[e];
    }
  }
  __syncthreads();   // staging done; no barriers until epilogue

  // per-lane V1s base: row (dt*16+c), col chunk (jh*3+m)*32 + quad*8
  // addr(dt,m) = base + dt*6400 + m*64 bytes (immediate offsets)
  const unsigned short* v1base = V1s + c * 200 + jh * 96 + (quad << 3);

  const v4f z = {0.f, 0.f, 0.f, 0.f};
  v4f acc[4] = {z, z, z, z};
  float sS = 0.f;

  union U4 { uint4 u4; unsigned short us[8]; };
  union AF { v8s v; unsigned u[4]; };

#pragma unroll 1
  for (int ks = 0; ks < 24; ++ks) {
    const int rl = kh * 24 + ks;             // row in K2s / block-local k
    U4 kl, khh;
    kl.u4  = *(const uint4*)(K2s + (rl << 6) + (quad << 3));
    khh.u4 = *(const uint4*)(K2s + (rl << 6) + (quad << 3) + 32);
    // v2: vt[dt][r] = v2[k][dt*16 + quad*4 + r]
    const float* vb = v2g + ((kb * 48 + rl) << 6) + (quad << 2);
    const v4f vt0 = *(const v4f*)(vb);
    const v4f vt1 = *(const v4f*)(vb + 16);
    const v4f vt2 = *(const v4f*)(vb + 32);
    const v4f vt3 = *(const v4f*)(vb + 48);

    AF af0, af1;  // B-frags of L-MFMA: (q*k2) for d-halves 0/1, col index = i = c
#pragma unroll
    for (int e = 0; e < 4; ++e) {
      af0.u[e] = pack_bf16(q0[2*e] * bf2f(kl.us[2*e]),  q0[2*e+1] * bf2f(kl.us[2*e+1]));
      af1.u[e] = pack_bf16(q1[2*e] * bf2f(khh.us[2*e]), q1[2*e+1] * bf2f(khh.us[2*e+1]));
    }

    v4f o0 = z, o1 = z, o2 = z, o3 = z;
#pragma unroll
    for (int m = 0; m < 3; ++m) {
      // SWAPPED logits: rows = k1 (j), cols = q (i); lane holds P[i=c][j=..quad*4+r]
      v4f Ca = MFMA32(k1f[2*m][0],   af0.v, z);
      Ca = MFMA32(k1f[2*m][1],   af1.v, Ca);
      v4f Cb = MFMA32(k1f[2*m+1][0], af0.v, z);
      Cb = MFMA32(k1f[2*m+1][1], af1.v, Cb);
#pragma unroll
      for (int r = 0; r < 4; ++r) { Ca[r] = EXP2F(Ca[r]); Cb[r] = EXP2F(Cb[r]); }
      sS += Ca[0] + Ca[1] + Ca[2] + Ca[3] + Cb[0] + Cb[1] + Cb[2] + Cb[3];
      AF pp;  // PV B-frag: pos e<4 -> jt-even r=e; e>=4 -> jt-odd r=e-4
      pp.u[0] = pack_bf16(Ca[0], Ca[1]);
      pp.u[1] = pack_bf16(Ca[2], Ca[3]);
      pp.u[2] = pack_bf16(Cb[0], Cb[1]);
      pp.u[3] = pack_bf16(Cb[2], Cb[3]);
      // PV A-frags from LDS (kstep-invariant addresses, 2-way bank alias)
      const v8s vf0 = *(const v8s*)(v1base + m * 32);
      const v8s vf1 = *(const v8s*)(v1base + 16 * 200 + m * 32);
      const v8s vf2 = *(const v8s*)(v1base + 32 * 200 + m * 32);
      const v8s vf3 = *(const v8s*)(v1base + 48 * 200 + m * 32);
      o0 = MFMA32(vf0, pp.v, o0);
      o1 = MFMA32(vf1, pp.v, o1);
      o2 = MFMA32(vf2, pp.v, o2);
      o3 = MFMA32(vf3, pp.v, o3);
    }
    acc[0] += o0 * vt0;
    acc[1] += o1 * vt1;
    acc[2] += o2 * vt2;
    acc[3] += o3 * vt3;
  }

  __syncthreads();  // reuse smem for cross-wave reduction
  float* redA = (float*)smem;              // [4][16 i][64 d]
  float* redS = (float*)smem + 4096;       // [4 wv][4 quad][16 i]

  // lane (c,quad): acc[dt][r] -> i=c, d=dt*16+quad*4+r (v4f rows contiguous)
#pragma unroll
  for (int dt = 0; dt < 4; ++dt)
    *(v4f*)(redA + wv * 1024 + (c << 6) + (dt << 4) + (quad << 2)) = acc[dt];
  redS[wv * 64 + (quad << 4) + c] = sS;
  __syncthreads();

  const int pbase = (bh * 12 + it) * 4 + kb;
  float* ap_out = accp + pbase * 1024;
  for (int idx = tid; idx < 1024; idx += 256)
    ap_out[idx] = redA[idx] + redA[1024 + idx] + redA[2048 + idx] + redA[3072 + idx];
  if (tid < 16) {
    float s = 0.f;
#pragma unroll
    for (int w = 0; w < 4; ++w)
#pragma unroll
      for (int qq = 0; qq < 4; ++qq)
        s += redS[w * 64 + qq * 16 + tid];
    Sp[pbase * 16 + tid] = s;
  }
}

// ------------------------------ Phase 3: fused norm + out GEMM -------------
// grid 96 x 256thr: blk = bit*4 + nq; bit -> (b, it) = 16 output rows;
// nq -> 128-col slab. Norm redundant x4 (L2-hit), GEMM depth-2 B prefetch.
__global__ __launch_bounds__(256) void outp2_kernel(
    const float* __restrict__ wsf, const unsigned short* __restrict__ wsh,
    const float* __restrict__ bout, float* __restrict__ y) {
  __shared__ unsigned short OHs[16 * 520];
  __shared__ unsigned short OLs[16 * 520];
  const float* accp = wsf + 393216;
  const float* Sp   = wsf + 1179648;

  const int tid = threadIdx.x;
  const int nq  = blockIdx.x & 3;
  const int bit = blockIdx.x >> 2;        // 0..23
  const int b = bit / 12, it = bit % 12;
  const int m0 = b * 192 + it * 16;       // output rows m0..m0+15

  // ---- norm phase: row i = tid>>4, cols cc0..cc0+31 ----
  {
    const int i = tid >> 4, cc0 = (tid & 15) * 32;
    const int h = cc0 >> 6;               // constant within the 32-col chunk
    const int pb = ((b * 8 + h) * 12 + it) * 4;
    const float inv = 1.0f / (Sp[pb * 16 + i] + Sp[(pb + 1) * 16 + i] +
                              Sp[(pb + 2) * 16 + i] + Sp[(pb + 3) * 16 + i]);
    const float* ap = accp + pb * 1024 + (i << 6) + (cc0 & 63);
#pragma unroll
    for (int g = 0; g < 8; ++g) {
      v4f a = *(const v4f*)(ap + g * 4);
      a += *(const v4f*)(ap + 1024 + g * 4);
      a += *(const v4f*)(ap + 2048 + g * 4);
      a += *(const v4f*)(ap + 3072 + g * 4);
#pragma unroll
      for (int j = 0; j < 4; ++j) {
        const float v = a[j] * inv;
        const unsigned short hh = f2bf(v);
        OHs[i * 520 + cc0 + g * 4 + j] = hh;
        OLs[i * 520 + cc0 + g * 4 + j] = f2bf(v - bf2f(hh));
      }
    }
  }
  __syncthreads();

  // ---- GEMM phase: wave wv covers 32 cols (2 n-tiles) ----
  const int lane = tid & 63, wv = tid >> 6;
  const int c = lane & 15, q = lane >> 4;
  const int n0w = nq * 128 + wv * 32;
  const v4f z = {0.f, 0.f, 0.f, 0.f};
  v4f acc[2] = {z, z};

  const unsigned short* Bhb = wsh + WOTH_OFF;
  const unsigned short* Blb = wsh + WOTL_OFF;

  // cB/nB layout: [nt*2 + 0]=Bh, [nt*2 + 1]=Bl
  v8s cB[4], nB[4];
#pragma unroll
  for (int nt = 0; nt < 2; ++nt) {
    const int n = n0w + nt * 16 + c;
    cB[nt * 2]     = *(const v8s*)(Bhb + n * 512 + (q << 3));
    cB[nt * 2 + 1] = *(const v8s*)(Blb + n * 512 + (q << 3));
    nB[nt * 2]     = *(const v8s*)(Bhb + n * 512 + 32 + (q << 3));
    nB[nt * 2 + 1] = *(const v8s*)(Blb + n * 512 + 32 + (q << 3));
  }

#pragma unroll 1
  for (int ks = 0; ks < 16; ++ks) {
    v8s x2[4];
    if (ks < 14) {
      const int o = (ks + 2) * 32 + (q << 3);
#pragma unroll
      for (int nt = 0; nt < 2; ++nt) {
        const int n = n0w + nt * 16 + c;
        x2[nt * 2]     = *(const v8s*)(Bhb + n * 512 + o);
        x2[nt * 2 + 1] = *(const v8s*)(Blb + n * 512 + o);
      }
    }
    const v8s Ah = *(const v8s*)(OHs + c * 520 + ks * 32 + (q << 3));
    const v8s Al = *(const v8s*)(OLs + c * 520 + ks * 32 + (q << 3));
#pragma unroll
    for (int nt = 0; nt < 2; ++nt) {
      acc[nt] = MFMA32(Al, cB[nt * 2],     acc[nt]);
      acc[nt] = MFMA32(Ah, cB[nt * 2 + 1], acc[nt]);
      acc[nt] = MFMA32(Ah, cB[nt * 2],     acc[nt]);
    }
#pragma unroll
    for (int i2 = 0; i2 < 4; ++i2) { cB[i2] = nB[i2]; nB[i2] = x2[i2]; }
  }

#pragma unroll
  for (int nt = 0; nt < 2; ++nt) {
    const int n = n0w + nt * 16 + c;
    const float bv = bout[n];
#pragma unroll
    for (int r = 0; r < 4; ++r)
      y[(m0 + (q << 2) + r) * 512 + n] = acc[nt][r] + bv;
  }
}

// ------------------------------ launcher -----------------------------------
extern "C" void kernel_launch(void* const* d_in, const int* in_sizes, int n_in,
                              void* d_out, int out_size, void* d_ws, size_t ws_size,
                              hipStream_t stream) {
  const float* x    = (const float*)d_in[0];
  const float* Win  = (const float*)d_in[1];
  const float* bin  = (const float*)d_in[2];
  const float* Wout = (const float*)d_in[3];
  const float* bout = (const float*)d_in[4];

  float* wsf = (float*)d_ws;
  unsigned short* wsh = (unsigned short*)(wsf + 1191936);
  float* accp = wsf + 393216;
  float* Sp   = wsf + 1179648;

  prep_kernel<<<dim3(864), 256, 0, stream>>>(x, Win, Wout, wsh);
  proj_kernel<<<dim3(960), 64, 0, stream>>>(wsh, bin, wsf, wsh);
  attn_kernel<<<dim3(768), 256, 0, stream>>>(wsf, wsh, accp, Sp);
  outp2_kernel<<<dim3(96), 256, 0, stream>>>(wsf, wsh, bout, (float*)d_out);
}